// Round 18
// baseline (229.026 us; speedup 1.0000x reference)
//
#include <hip/hip_runtime.h>
#include <hip/hip_bf16.h>

#define N_NODES 100000
#define N_EDGES 1600000
#define DF 64

#define BSHIFT 9                       // 512 nodes per bucket
#define NBUCK ((N_NODES + 511) >> 9)   // 196
#define NBPAD 256
#define CHUNK 4096                     // edges per scatter block
#define CAP 10240                      // LDS slice capacity (mean 8192, +22 sigma)
#define CAPR 10240                     // fixed staging window per bucket
#define DBINS 256                      // degree-sort bins (deg clamped to 255)

typedef unsigned int uint;
typedef unsigned short ushort;
typedef unsigned char uchar;
typedef __attribute__((ext_vector_type(8))) short short8;
typedef __attribute__((ext_vector_type(4))) float f32x4;
typedef __attribute__((ext_vector_type(4))) uint uintx4;

__device__ __forceinline__ uint pack2_rne(float a, float b) {
    uint ua = __float_as_uint(a); ua = (ua + 0x7fffu + ((ua >> 16) & 1u)) >> 16;
    uint ub = __float_as_uint(b); ub = (ub + 0x7fffu + ((ub >> 16) & 1u)) >> 16;
    return ua | (ub << 16);
}
__device__ __forceinline__ ushort pack1_rne(float a) {
    uint u = __float_as_uint(a);
    return (ushort)((u + 0x7fffu + ((u >> 16) & 1u)) >> 16);
}

// ---------------- prologue: weights (blocks 0..95) + cursors/bias (block 96) ----------------
__global__ __launch_bounds__(256) void prep_kernel(
        const float* __restrict__ Wsd, const float* __restrict__ Wds,
        const float* __restrict__ b_sd, const float* __restrict__ b_ds,
        ushort* __restrict__ Wb, float* __restrict__ bias_tot,
        int* __restrict__ cur_r, int* __restrict__ cur_c,
        int* __restrict__ dhist) {            // dhist: 2*DBINS ints, zeroed here
    int i = blockIdx.x * 256 + threadIdx.x;
    if (i < 6 * 4096) {
        int m = i >> 12, r = i & 4095;
        int lv = (m >= 3) ? (m - 3) : m;
        float scale = 0.5f * ((lv == 0) ? 1.f : ((lv == 1) ? 0.5f : 0.25f));
        float v = ((m < 3) ? Wsd[lv * 4096 + r] : Wds[lv * 4096 + r]) * scale;
        Wb[i] = pack1_rne(v);
    } else if (blockIdx.x == 96) {
        int t = threadIdx.x;
        if (t < NBUCK) { cur_r[t] = t * CAPR; cur_c[t] = t * CAPR; }
        if (t >= 192) {
            int o = t - 192;
            float s = 0.f, sc = 1.f;
            for (int l = 0; l < 3; ++l) {
                s += sc * (0.5f * b_sd[l * 64 + o] + 0.5f * b_ds[l * 64 + o]);
                sc *= 0.5f;
            }
            bias_tot[o] = s;
        }
    } else if (blockIdx.x == 97) {
        int t = threadIdx.x;
        dhist[t] = 0;
        dhist[DBINS + t] = 0;
    }
}

// ---------------- scatter: one direction per block; fully parallel flush ----------------
__global__ __launch_bounds__(256) void scatter_split_kernel(
        const int* __restrict__ row, const int* __restrict__ col,
        int* __restrict__ cur_r, int* __restrict__ cur_c,
        uint* __restrict__ stg_r, uint* __restrict__ stg_c, int E, int ablk) {
    __shared__ uint stage[CHUNK];    // 16 KB
    __shared__ uchar bkt[CHUNK];     // 4 KB
    __shared__ int cnt[NBPAD], scn[NBPAD], curL[NBPAD], gb[NBPAD];
    int t = threadIdx.x;
    int bid = blockIdx.x;
    int dir = (bid >= ablk);
    int cid = dir ? (bid - ablk) : bid;
    const int* key = dir ? col : row;
    const int* oth = dir ? row : col;
    int* cursors   = dir ? cur_c : cur_r;
    uint* staging  = dir ? stg_c : stg_r;
    int e0 = cid * CHUNK;
    int tot = min(E - e0, CHUNK);
    cnt[t] = 0; curL[t] = 0;
    __syncthreads();
    for (int i = t; i < tot; i += 256)
        atomicAdd(&cnt[key[e0 + i] >> BSHIFT], 1);
    __syncthreads();
    int v = cnt[t];
    scn[t] = v;
    __syncthreads();
    for (int off = 1; off < 256; off <<= 1) {
        int a = (t >= off) ? scn[t - off] : 0;
        __syncthreads();
        scn[t] += a;
        __syncthreads();
    }
    int excl = scn[t] - v;
    if (t < NBUCK && v > 0) gb[t] = atomicAdd(&cursors[t], v);
    __syncthreads();
    scn[t] = excl;
    __syncthreads();
    for (int i = t; i < tot; i += 256) {
        int k = key[e0 + i], c = oth[e0 + i];
        int b = k >> BSHIFT;
        int pos = scn[b] + atomicAdd(&curL[b], 1);
        stage[pos] = ((uint)(k & 511) << 17) | (uint)c;
        bkt[pos] = (uchar)b;
    }
    __syncthreads();
    for (int i = t; i < tot; i += 256) {
        int b = bkt[i];
        staging[gb[b] + (i - scn[b])] = stage[i];
    }
}

// ---------------- per bucket (both dirs): bucket-scan + degree hist -> ptr + dp + CSR + deg hist ----
__global__ __launch_bounds__(512) void degptr_build2_kernel(
        const int* __restrict__ cur_r, const int* __restrict__ cur_c,
        const uint* __restrict__ stg_r, const uint* __restrict__ stg_c,
        int* __restrict__ row_ptr, int* __restrict__ col_ptr,
        float* __restrict__ dp_out, float* __restrict__ dp_in,
        int* __restrict__ csr_r, int* __restrict__ csr_c,
        int* __restrict__ dhist, int n) {
    __shared__ int cnt[512];
    __shared__ int sc[512];
    __shared__ int bs[256];
    __shared__ int dh[DBINS];
    __shared__ int slice[CAP];
    int blk = blockIdx.x, t = threadIdx.x;
    int dir = (blk >= NBUCK);
    int b = dir ? (blk - NBUCK) : blk;
    const int*  cur     = dir ? cur_c : cur_r;
    const uint* staging = dir ? stg_c : stg_r;
    int* ptr = dir ? col_ptr : row_ptr;
    float* dp = dir ? dp_in : dp_out;
    int* csr = dir ? csr_c : csr_r;
    int* dhg = dhist + dir * DBINS;

    // inline exclusive scan of the 196 bucket counts -> this bucket's CSR base
    if (t < 256) bs[t] = (t < NBUCK) ? (cur[t] - t * CAPR) : 0;
    if (t < DBINS) dh[t] = 0;
    __syncthreads();
    for (int off = 1; off < 256; off <<= 1) {
        int a = (t >= off && t < 256) ? bs[t - off] : 0;
        __syncthreads();
        if (t < 256) bs[t] += a;
        __syncthreads();
    }
    int c0 = (b == 0) ? 0 : bs[b - 1];

    int lo = b << BSHIFT;
    int nn = min(n - lo, 512);
    int s0 = b * CAPR;
    int s1 = cur[b];
    int S = s1 - s0;
    cnt[t] = 0;
    __syncthreads();
    for (int i = s0 + t; i < s1; i += 512)
        atomicAdd(&cnt[staging[i] >> 17], 1);
    __syncthreads();
    int v = cnt[t];
    sc[t] = v;
    __syncthreads();
    for (int off = 1; off < 512; off <<= 1) {
        int a = (t >= off) ? sc[t - off] : 0;
        __syncthreads();
        sc[t] += a;
        __syncthreads();
    }
    int excl = sc[t] - v;
    if (t < nn) {
        ptr[lo + t] = c0 + excl;
        dp[lo + t] = (v > 0) ? rsqrtf(sqrtf((float)v)) : 0.f;
        atomicAdd(&dh[min(v, DBINS - 1)], 1);
    }
    if (lo + t == n - 1) ptr[n] = c0 + sc[t];
    __syncthreads();
    if (t < DBINS && dh[t] > 0) atomicAdd(&dhg[t], dh[t]);
    sc[t] = excl;      // per-node exclusive offsets
    cnt[t] = 0;        // reuse as build cursor
    __syncthreads();
    if (S <= CAP) {
        for (int i = s0 + t; i < s1; i += 512) {
            uint w = staging[i];
            int rl = (int)(w >> 17), c = (int)(w & 0x1FFFFu);
            int pos = sc[rl] + atomicAdd(&cnt[rl], 1);
            slice[pos] = c;
        }
        __syncthreads();
        for (int i = t; i < S; i += 512) csr[c0 + i] = slice[i];
    } else {  // safety fallback
        for (int i = s0 + t; i < s1; i += 512) {
            uint w = staging[i];
            int rl = (int)(w >> 17), c = (int)(w & 0x1FFFFu);
            int pos = c0 + sc[rl] + atomicAdd(&cnt[rl], 1);
            csr[pos] = c;
        }
    }
}

// ---------------- scan degree hists -> bin cursors (both dirs, 1 block) ----------------
__global__ void dscan_kernel(const int* __restrict__ dhist,
                             int* __restrict__ dcur_r, int* __restrict__ dcur_c) {
    __shared__ int s[DBINS];
    int t = threadIdx.x;
    int v = dhist[t];
    s[t] = v; __syncthreads();
    for (int off = 1; off < DBINS; off <<= 1) {
        int a = (t >= off) ? s[t - off] : 0; __syncthreads();
        s[t] += a; __syncthreads();
    }
    dcur_r[t] = s[t] - v;
    __syncthreads();
    int v2 = dhist[DBINS + t];
    s[t] = v2; __syncthreads();
    for (int off = 1; off < DBINS; off <<= 1) {
        int a = (t >= off) ? s[t - off] : 0; __syncthreads();
        s[t] += a; __syncthreads();
    }
    dcur_c[t] = s[t] - v2;
}

// ---------------- build degree-sorted perm (two-level counting sort) ----------------
__global__ __launch_bounds__(512) void perm_kernel(
        const int* __restrict__ row_ptr, const int* __restrict__ col_ptr,
        int* __restrict__ dcur_r, int* __restrict__ dcur_c,
        int* __restrict__ perm_r, int* __restrict__ perm_c, int n) {
    __shared__ int lcnt[DBINS];
    __shared__ int gbase[DBINS];
    __shared__ int lcur[DBINS];
    int blk = blockIdx.x, t = threadIdx.x;
    int dir = (blk >= NBUCK);
    int b = dir ? (blk - NBUCK) : blk;
    const int* ptr = dir ? col_ptr : row_ptr;
    int* dcur = dir ? dcur_c : dcur_r;
    int* perm = dir ? perm_c : perm_r;
    int lo = b << BSHIFT;
    int nn = min(n - lo, 512);
    if (t < DBINS) { lcnt[t] = 0; lcur[t] = 0; }
    __syncthreads();
    int d = -1;
    if (t < nn) {
        d = min(ptr[lo + t + 1] - ptr[lo + t], DBINS - 1);
        atomicAdd(&lcnt[d], 1);
    }
    __syncthreads();
    if (t < DBINS && lcnt[t] > 0) gbase[t] = atomicAdd(&dcur[t], lcnt[t]);
    __syncthreads();
    if (t < nn) {
        int pos = gbase[d] + atomicAdd(&lcur[d], 1);
        perm[pos] = lo + t;
    }
}

// ---------------- x -> bf16 pre-scaled only (dp_in * x) ----------------
__global__ __launch_bounds__(256) void cvt_scaled_kernel(
        const float* __restrict__ in, const float* __restrict__ dp,
        uint* __restrict__ scl, int n8) {
    int i = blockIdx.x * blockDim.x + threadIdx.x;   // 8 floats per thread
    if (i >= n8) return;
    float d = dp[i >> 3];
    const float4 a = ((const float4*)in)[i * 2];
    const float4 b = ((const float4*)in)[i * 2 + 1];
    uintx4 s_;
    s_.x = pack2_rne(a.x * d, a.y * d); s_.y = pack2_rne(a.z * d, a.w * d);
    s_.z = pack2_rne(b.x * d, b.y * d); s_.w = pack2_rne(b.z * d, b.w * d);
    *(uintx4*)&scl[i * 4] = s_;
}

#define ACC8(u)                                        \
    acc[0] += __uint_as_float((u).x << 16);            \
    acc[1] += __uint_as_float((u).x & 0xffff0000u);    \
    acc[2] += __uint_as_float((u).y << 16);            \
    acc[3] += __uint_as_float((u).y & 0xffff0000u);    \
    acc[4] += __uint_as_float((u).z << 16);            \
    acc[5] += __uint_as_float((u).z & 0xffff0000u);    \
    acc[6] += __uint_as_float((u).w << 16);            \
    acc[7] += __uint_as_float((u).w & 0xffff0000u);

// ---------------- forward SpMM: 4 nodes/wave (degree-sorted via perm) ----------------
__global__ __launch_bounds__(256) void spmm_fwd_kernel(
        const int* __restrict__ ptr, const int* __restrict__ nbr,
        const int* __restrict__ perm,
        const float* __restrict__ dp_dst, const float* __restrict__ dp_nxt,
        const ushort* __restrict__ srcs,
        ushort* __restrict__ y_raw, ushort* __restrict__ y_scl, int n, int wscl) {
    int wv = (blockIdx.x * blockDim.x + threadIdx.x) >> 6;
    int lane = threadIdx.x & 63;
    int idx = wv * 4 + (lane >> 4);
    int subl = lane & 15;
    int slot = subl >> 3;     // 0..1
    int d8   = subl & 7;      // 8-bf16 group
    bool valid = idx < n;
    int node = valid ? perm[idx] : 0;
    int beg = valid ? ptr[node] : 0;
    int end = valid ? ptr[node + 1] : 0;
    float acc[8] = {};
    int p = beg + slot;
    for (; p + 6 < end; p += 8) {   // unroll x4: four independent gathers in flight
        int c0 = nbr[p];
        int c1 = nbr[p + 2];
        int c2 = nbr[p + 4];
        int c3 = nbr[p + 6];
        const uintx4 u0 = *(const uintx4*)&srcs[(size_t)c0 * DF + d8 * 8];
        const uintx4 u1 = *(const uintx4*)&srcs[(size_t)c1 * DF + d8 * 8];
        const uintx4 u2 = *(const uintx4*)&srcs[(size_t)c2 * DF + d8 * 8];
        const uintx4 u3 = *(const uintx4*)&srcs[(size_t)c3 * DF + d8 * 8];
        ACC8(u0);
        ACC8(u1);
        ACC8(u2);
        ACC8(u3);
    }
    for (; p < end; p += 2) {
        int c0 = nbr[p];
        const uintx4 u0 = *(const uintx4*)&srcs[(size_t)c0 * DF + d8 * 8];
        ACC8(u0);
    }
    // reduce over the 2 slots (xor 8 — stays within each 16-lane group)
#pragma unroll
    for (int j = 0; j < 8; ++j) acc[j] += __shfl_xor(acc[j], 8);
    if (slot == 0 && valid) {
        float s = dp_dst[node];
        float r0 = acc[0] * s, r1 = acc[1] * s, r2 = acc[2] * s, r3 = acc[3] * s;
        float r4 = acc[4] * s, r5 = acc[5] * s, r6 = acc[6] * s, r7 = acc[7] * s;
        uintx4 o;
        o.x = pack2_rne(r0, r1); o.y = pack2_rne(r2, r3);
        o.z = pack2_rne(r4, r5); o.w = pack2_rne(r6, r7);
        *(uintx4*)&y_raw[(size_t)node * DF + d8 * 8] = o;
        if (wscl) {
            float d = dp_nxt[node];
            uintx4 q;
            q.x = pack2_rne(r0 * d, r1 * d); q.y = pack2_rne(r2 * d, r3 * d);
            q.z = pack2_rne(r4 * d, r5 * d); q.w = pack2_rne(r6 * d, r7 * d);
            *(uintx4*)&y_scl[(size_t)node * DF + d8 * 8] = q;
        }
    }
}

// ---------------- final: 4 nodes/wave (degree-sorted); out = oh + dp_in*sum + bias ----------------
__global__ __launch_bounds__(256) void spmm_final_kernel(
        const int* __restrict__ ptr, const int* __restrict__ nbr,
        const int* __restrict__ perm,
        const float* __restrict__ dp_dst,
        const ushort* __restrict__ zb, const ushort* __restrict__ oh,
        const float* __restrict__ bias_tot, float* __restrict__ out, int n) {
    int wv = (blockIdx.x * blockDim.x + threadIdx.x) >> 6;
    int lane = threadIdx.x & 63;
    int idx = wv * 4 + (lane >> 4);
    int subl = lane & 15;
    int slot = subl >> 3;
    int d8   = subl & 7;
    bool valid = idx < n;
    int node = valid ? perm[idx] : 0;
    int beg = valid ? ptr[node] : 0;
    int end = valid ? ptr[node + 1] : 0;
    float acc[8] = {};
    int p = beg + slot;
    for (; p + 6 < end; p += 8) {
        int c0 = nbr[p];
        int c1 = nbr[p + 2];
        int c2 = nbr[p + 4];
        int c3 = nbr[p + 6];
        const uintx4 u0 = *(const uintx4*)&zb[(size_t)c0 * DF + d8 * 8];
        const uintx4 u1 = *(const uintx4*)&zb[(size_t)c1 * DF + d8 * 8];
        const uintx4 u2 = *(const uintx4*)&zb[(size_t)c2 * DF + d8 * 8];
        const uintx4 u3 = *(const uintx4*)&zb[(size_t)c3 * DF + d8 * 8];
        ACC8(u0);
        ACC8(u1);
        ACC8(u2);
        ACC8(u3);
    }
    for (; p < end; p += 2) {
        int c0 = nbr[p];
        const uintx4 u0 = *(const uintx4*)&zb[(size_t)c0 * DF + d8 * 8];
        ACC8(u0);
    }
#pragma unroll
    for (int j = 0; j < 8; ++j) acc[j] += __shfl_xor(acc[j], 8);
    if (slot == 0 && valid) {
        float s = dp_dst[node];
        const uintx4 h = *(const uintx4*)&oh[(size_t)node * DF + d8 * 8];
        const float4 b0 = *(const float4*)&bias_tot[d8 * 8];
        const float4 b1 = *(const float4*)&bias_tot[d8 * 8 + 4];
        f32x4 p0, p1;
        p0.x = __uint_as_float(h.x << 16)         + s * acc[0] + b0.x;
        p0.y = __uint_as_float(h.x & 0xffff0000u) + s * acc[1] + b0.y;
        p0.z = __uint_as_float(h.y << 16)         + s * acc[2] + b0.z;
        p0.w = __uint_as_float(h.y & 0xffff0000u) + s * acc[3] + b0.w;
        p1.x = __uint_as_float(h.z << 16)         + s * acc[4] + b1.x;
        p1.y = __uint_as_float(h.z & 0xffff0000u) + s * acc[5] + b1.y;
        p1.z = __uint_as_float(h.w << 16)         + s * acc[6] + b1.z;
        p1.w = __uint_as_float(h.w & 0xffff0000u) + s * acc[7] + b1.w;
        float* op = &out[(size_t)node * DF + d8 * 8];
        *(f32x4*)op = p0;
        *(f32x4*)(op + 4) = p1;
    }
}

// ---------------- fused MFMA GEMM (x read as fp32, converted inline):
//   oh  = bf16( y0*Wb0^T + y1*Wb1^T + y2*Wb2^T )              (0.5*scale in Wb)
//   zb' = bf16( dp_out[row] * (x*Wb3^T + y1*Wb4^T + y2*Wb5^T) )
__global__ __launch_bounds__(256) void gemm_fused_kernel(
        const ushort* __restrict__ y0, const ushort* __restrict__ y1,
        const ushort* __restrict__ y2, const float* __restrict__ xf,
        const ushort* __restrict__ Wb, const float* __restrict__ dp_out,
        ushort* __restrict__ oh, ushort* __restrict__ zb, int n) {
    __shared__ ushort wlds[6 * 4096];
    int t = threadIdx.x;
    for (int f = t; f < 3072; f += 256) {
        int c  = f & 15;
        int kq = (f >> 4) & 3;
        int ks = (f >> 6) & 1;
        int cb = (f >> 7) & 3;
        int m  = f >> 9;
        const uintx4 v = *(const uintx4*)&Wb[m * 4096 + (16 * cb + c) * 64 + ks * 32 + kq * 8];
        *(uintx4*)&wlds[f * 8] = v;
    }
    __syncthreads();
    int w = t >> 6, lane = t & 63;
    int node0 = blockIdx.x * 64 + w * 16;
    int arow = node0 + (lane & 15);
    int kqo = (lane >> 4) * 8;
    f32x4 accO[4] = {};
    f32x4 accZ[4] = {};
#pragma unroll
    for (int ks = 0; ks < 2; ++ks) {
        int aoff = ks * 32 + kqo;
        short8 a0 = {}, a1 = {}, a2 = {}, ax = {};
        if (arow < n) {
            a0 = *(const short8*)&y0[(size_t)arow * DF + aoff];
            a1 = *(const short8*)&y1[(size_t)arow * DF + aoff];
            a2 = *(const short8*)&y2[(size_t)arow * DF + aoff];
            const float4 xa = *(const float4*)&xf[(size_t)arow * DF + aoff];
            const float4 xc = *(const float4*)&xf[(size_t)arow * DF + aoff + 4];
            uintx4 xp;
            xp.x = pack2_rne(xa.x, xa.y); xp.y = pack2_rne(xa.z, xa.w);
            xp.z = pack2_rne(xc.x, xc.y); xp.w = pack2_rne(xc.z, xc.w);
            ax = *(short8*)&xp;
        }
#pragma unroll
        for (int cb = 0; cb < 4; ++cb) {
            const ushort* bp = &wlds[(((cb * 2 + ks) * 64) + lane) * 8];
            short8 b0 = *(const short8*)(bp);
            short8 b1 = *(const short8*)(bp + 4096);
            short8 b2 = *(const short8*)(bp + 8192);
            short8 b3 = *(const short8*)(bp + 12288);
            short8 b4 = *(const short8*)(bp + 16384);
            short8 b5 = *(const short8*)(bp + 20480);
            accO[cb] = __builtin_amdgcn_mfma_f32_16x16x32_bf16(a0, b0, accO[cb], 0, 0, 0);
            accO[cb] = __builtin_amdgcn_mfma_f32_16x16x32_bf16(a1, b1, accO[cb], 0, 0, 0);
            accO[cb] = __builtin_amdgcn_mfma_f32_16x16x32_bf16(a2, b2, accO[cb], 0, 0, 0);
            accZ[cb] = __builtin_amdgcn_mfma_f32_16x16x32_bf16(ax, b3, accZ[cb], 0, 0, 0);
            accZ[cb] = __builtin_amdgcn_mfma_f32_16x16x32_bf16(a1, b4, accZ[cb], 0, 0, 0);
            accZ[cb] = __builtin_amdgcn_mfma_f32_16x16x32_bf16(a2, b5, accZ[cb], 0, 0, 0);
        }
    }
#pragma unroll
    for (int r = 0; r < 4; ++r) {
        int nd = node0 + (lane >> 4) * 4 + r;
        if (nd < n) {
            float d = dp_out[nd];
#pragma unroll
            for (int cb = 0; cb < 4; ++cb) {
                int o = cb * 16 + (lane & 15);
                oh[(size_t)nd * DF + o] = pack1_rne(accO[cb][r]);
                zb[(size_t)nd * DF + o] = pack1_rne(accZ[cb][r] * d);
            }
        }
    }
}

extern "C" void kernel_launch(void* const* d_in, const int* in_sizes, int n_in,
                              void* d_out, int out_size, void* d_ws, size_t ws_size,
                              hipStream_t stream) {
    const int N = N_NODES, E = N_EDGES;
    const float* x    = (const float*)d_in[0];
    const int*   ei   = (const int*)d_in[1];
    const int*   row  = ei;
    const int*   col  = ei + E;
    const float* W_sd = (const float*)d_in[2];
    const float* b_sd = (const float*)d_in[3];
    const float* W_ds = (const float*)d_in[4];
    const float* b_ds = (const float*)d_in[5];
    float* out = (float*)d_out;

    char* ws = (char*)d_ws;
    size_t off = 0;
    auto alloc = [&](size_t bytes) -> void* {
        void* p = ws + off;
        off += (bytes + 255) & ~(size_t)255;
        return p;
    };
    int*   cur_r     = (int*)alloc((size_t)NBUCK * 4);
    int*   cur_c     = (int*)alloc((size_t)NBUCK * 4);
    int*   row_ptr   = (int*)alloc((size_t)(N + 1) * 4);
    int*   col_ptr   = (int*)alloc((size_t)(N + 1) * 4);
    float* dp_out    = (float*)alloc((size_t)N * 4);
    float* dp_in     = (float*)alloc((size_t)N * 4);
    int*   csr_row_col = (int*)alloc((size_t)E * 4);
    int*   csr_col_row = (int*)alloc((size_t)E * 4);
    float* bias_tot  = (float*)alloc(64 * 4);
    int*   dhist     = (int*)alloc((size_t)2 * DBINS * 4);
    int*   dcur_r    = (int*)alloc((size_t)DBINS * 4);
    int*   dcur_c    = (int*)alloc((size_t)DBINS * 4);
    int*   perm_r    = (int*)alloc((size_t)N * 4);
    int*   perm_c    = (int*)alloc((size_t)N * 4);
    ushort* Wb   = (ushort*)alloc((size_t)6 * 4096 * 2);
    ushort* x_s  = (ushort*)alloc((size_t)N * DF * 2);
    ushort* y0   = (ushort*)alloc((size_t)N * DF * 2);
    ushort* y1   = (ushort*)alloc((size_t)N * DF * 2);
    ushort* y2   = (ushort*)alloc((size_t)N * DF * 2);
    ushort* bufA = (ushort*)alloc((size_t)N * DF * 2);  // stg_r -> y0s -> zb
    ushort* bufB = (ushort*)alloc((size_t)N * DF * 2);  // stg_c -> y1s -> oh
    // timeline overlays (each 12.8 MB; staging needs NBUCK*CAPR*4 = 8.03 MB)
    uint*   stg_r = (uint*)bufA;
    uint*   stg_c = (uint*)bufB;
    ushort* y0s = bufA;
    ushort* y1s = bufB;
    ushort* zb  = bufA;
    ushort* oh  = bufB;

    // prologue: weights + bias + staging cursors + degree-hist zero (one kernel)
    prep_kernel<<<98, 256, 0, stream>>>(W_sd, W_ds, b_sd, b_ds, Wb, bias_tot,
                                        cur_r, cur_c, dhist);

    const int ablk = (E + CHUNK - 1) / CHUNK;  // 391
    scatter_split_kernel<<<2 * ablk, 256, 0, stream>>>(row, col, cur_r, cur_c,
                                                       stg_r, stg_c, E, ablk);
    degptr_build2_kernel<<<2 * NBUCK, 512, 0, stream>>>(
        cur_r, cur_c, stg_r, stg_c,
        row_ptr, col_ptr, dp_out, dp_in, csr_row_col, csr_col_row, dhist, N);
    dscan_kernel<<<1, DBINS, 0, stream>>>(dhist, dcur_r, dcur_c);
    perm_kernel<<<2 * NBUCK, 512, 0, stream>>>(row_ptr, col_ptr, dcur_r, dcur_c,
                                               perm_r, perm_c, N);

    const int n8 = N * DF / 8;
    cvt_scaled_kernel<<<(n8 + 255) / 256, 256, 0, stream>>>(x, dp_in, (uint*)x_s, n8);

    const int spmm_blk = (N * 16 + 255) / 256;   // 4 nodes per wave
    const int gblk = (N + 63) / 64;

    // forward chain (degree-sorted node order; gathers read pre-scaled tables)
    spmm_fwd_kernel<<<spmm_blk, 256, 0, stream>>>(row_ptr, csr_row_col, perm_r,
                                                  dp_out, dp_in, x_s, y0, y0s, N, 1);
    spmm_fwd_kernel<<<spmm_blk, 256, 0, stream>>>(row_ptr, csr_row_col, perm_r,
                                                  dp_out, dp_in, y0s, y1, y1s, N, 1);
    spmm_fwd_kernel<<<spmm_blk, 256, 0, stream>>>(row_ptr, csr_row_col, perm_r,
                                                  dp_out, dp_in, y1s, y2, (ushort*)0, N, 0);

    // oh = bf16(0.5*sum y_i Wsd_i^T) ; zb = bf16(dp_out * 0.5*(x Wds0 + 0.5 y1 Wds1 + 0.25 y2 Wds2))
    gemm_fused_kernel<<<gblk, 256, 0, stream>>>(y0, y1, y2, x, Wb, dp_out, oh, zb, N);

    // out = oh + dp_in * (A^T-gather of zb) + bias
    spmm_final_kernel<<<spmm_blk, 256, 0, stream>>>(col_ptr, csr_col_row, perm_c,
                                                    dp_in, zb, oh, bias_tot, out, N);
}

// Round 19
// 213.836 us; speedup vs baseline: 1.0710x; 1.0710x over previous
//
#include <hip/hip_runtime.h>
#include <hip/hip_bf16.h>

#define N_NODES 100000
#define N_EDGES 1600000
#define DF 64

#define BSHIFT 9                       // 512 nodes per bucket
#define NBUCK ((N_NODES + 511) >> 9)   // 196
#define NBPAD 256
#define CHUNK 4096                     // edges per scatter block
#define CAP 10240                      // LDS slice capacity (mean 8192, +22 sigma)
#define CAPR 10240                     // fixed staging window per bucket

typedef unsigned int uint;
typedef unsigned short ushort;
typedef unsigned char uchar;
typedef __attribute__((ext_vector_type(8))) short short8;
typedef __attribute__((ext_vector_type(4))) float f32x4;
typedef __attribute__((ext_vector_type(4))) uint uintx4;

__device__ __forceinline__ uint pack2_rne(float a, float b) {
    uint ua = __float_as_uint(a); ua = (ua + 0x7fffu + ((ua >> 16) & 1u)) >> 16;
    uint ub = __float_as_uint(b); ub = (ub + 0x7fffu + ((ub >> 16) & 1u)) >> 16;
    return ua | (ub << 16);
}
__device__ __forceinline__ ushort pack1_rne(float a) {
    uint u = __float_as_uint(a);
    return (ushort)((u + 0x7fffu + ((u >> 16) & 1u)) >> 16);
}

// ---------------- prologue: weights (blocks 0..95) + cursors/bias (block 96) ----------------
__global__ __launch_bounds__(256) void prep_kernel(
        const float* __restrict__ Wsd, const float* __restrict__ Wds,
        const float* __restrict__ b_sd, const float* __restrict__ b_ds,
        ushort* __restrict__ Wb, float* __restrict__ bias_tot,
        int* __restrict__ cur_r, int* __restrict__ cur_c) {
    int i = blockIdx.x * 256 + threadIdx.x;
    if (i < 6 * 4096) {
        int m = i >> 12, r = i & 4095;
        int lv = (m >= 3) ? (m - 3) : m;
        float scale = 0.5f * ((lv == 0) ? 1.f : ((lv == 1) ? 0.5f : 0.25f));
        float v = ((m < 3) ? Wsd[lv * 4096 + r] : Wds[lv * 4096 + r]) * scale;
        Wb[i] = pack1_rne(v);
    } else if (blockIdx.x == 96) {
        int t = threadIdx.x;
        if (t < NBUCK) { cur_r[t] = t * CAPR; cur_c[t] = t * CAPR; }
        if (t >= 192) {
            int o = t - 192;
            float s = 0.f, sc = 1.f;
            for (int l = 0; l < 3; ++l) {
                s += sc * (0.5f * b_sd[l * 64 + o] + 0.5f * b_ds[l * 64 + o]);
                sc *= 0.5f;
            }
            bias_tot[o] = s;
        }
    }
}

// ---------------- scatter: one direction per block; fully parallel flush ----------------
__global__ __launch_bounds__(256) void scatter_split_kernel(
        const int* __restrict__ row, const int* __restrict__ col,
        int* __restrict__ cur_r, int* __restrict__ cur_c,
        uint* __restrict__ stg_r, uint* __restrict__ stg_c, int E, int ablk) {
    __shared__ uint stage[CHUNK];    // 16 KB
    __shared__ uchar bkt[CHUNK];     // 4 KB
    __shared__ int cnt[NBPAD], scn[NBPAD], curL[NBPAD], gb[NBPAD];
    int t = threadIdx.x;
    int bid = blockIdx.x;
    int dir = (bid >= ablk);
    int cid = dir ? (bid - ablk) : bid;
    const int* key = dir ? col : row;
    const int* oth = dir ? row : col;
    int* cursors   = dir ? cur_c : cur_r;
    uint* staging  = dir ? stg_c : stg_r;
    int e0 = cid * CHUNK;
    int tot = min(E - e0, CHUNK);
    cnt[t] = 0; curL[t] = 0;
    __syncthreads();
    for (int i = t; i < tot; i += 256)
        atomicAdd(&cnt[key[e0 + i] >> BSHIFT], 1);
    __syncthreads();
    int v = cnt[t];
    scn[t] = v;
    __syncthreads();
    for (int off = 1; off < 256; off <<= 1) {
        int a = (t >= off) ? scn[t - off] : 0;
        __syncthreads();
        scn[t] += a;
        __syncthreads();
    }
    int excl = scn[t] - v;
    if (t < NBUCK && v > 0) gb[t] = atomicAdd(&cursors[t], v);
    __syncthreads();
    scn[t] = excl;
    __syncthreads();
    for (int i = t; i < tot; i += 256) {
        int k = key[e0 + i], c = oth[e0 + i];
        int b = k >> BSHIFT;
        int pos = scn[b] + atomicAdd(&curL[b], 1);
        stage[pos] = ((uint)(k & 511) << 17) | (uint)c;
        bkt[pos] = (uchar)b;
    }
    __syncthreads();
    for (int i = t; i < tot; i += 256) {
        int b = bkt[i];
        staging[gb[b] + (i - scn[b])] = stage[i];
    }
}

// ---------------- per bucket (both dirs): bucket-scan + degree hist -> ptr + dp + CSR ----------------
__global__ __launch_bounds__(512) void degptr_build2_kernel(
        const int* __restrict__ cur_r, const int* __restrict__ cur_c,
        const uint* __restrict__ stg_r, const uint* __restrict__ stg_c,
        int* __restrict__ row_ptr, int* __restrict__ col_ptr,
        float* __restrict__ dp_out, float* __restrict__ dp_in,
        int* __restrict__ csr_r, int* __restrict__ csr_c, int n) {
    __shared__ int cnt[512];
    __shared__ int sc[512];
    __shared__ int bs[256];
    __shared__ int slice[CAP];
    int blk = blockIdx.x, t = threadIdx.x;
    int dir = (blk >= NBUCK);
    int b = dir ? (blk - NBUCK) : blk;
    const int*  cur     = dir ? cur_c : cur_r;
    const uint* staging = dir ? stg_c : stg_r;
    int* ptr = dir ? col_ptr : row_ptr;
    float* dp = dir ? dp_in : dp_out;
    int* csr = dir ? csr_c : csr_r;

    // inline exclusive scan of the 196 bucket counts -> this bucket's CSR base
    if (t < 256) bs[t] = (t < NBUCK) ? (cur[t] - t * CAPR) : 0;
    __syncthreads();
    for (int off = 1; off < 256; off <<= 1) {
        int a = (t >= off && t < 256) ? bs[t - off] : 0;
        __syncthreads();
        if (t < 256) bs[t] += a;
        __syncthreads();
    }
    int c0 = (b == 0) ? 0 : bs[b - 1];

    int lo = b << BSHIFT;
    int nn = min(n - lo, 512);
    int s0 = b * CAPR;
    int s1 = cur[b];
    int S = s1 - s0;
    cnt[t] = 0;
    __syncthreads();
    for (int i = s0 + t; i < s1; i += 512)
        atomicAdd(&cnt[staging[i] >> 17], 1);
    __syncthreads();
    int v = cnt[t];
    sc[t] = v;
    __syncthreads();
    for (int off = 1; off < 512; off <<= 1) {
        int a = (t >= off) ? sc[t - off] : 0;
        __syncthreads();
        sc[t] += a;
        __syncthreads();
    }
    int excl = sc[t] - v;
    if (t < nn) {
        ptr[lo + t] = c0 + excl;
        dp[lo + t] = (v > 0) ? rsqrtf(sqrtf((float)v)) : 0.f;
    }
    if (lo + t == n - 1) ptr[n] = c0 + sc[t];
    __syncthreads();
    sc[t] = excl;      // per-node exclusive offsets
    cnt[t] = 0;        // reuse as build cursor
    __syncthreads();
    if (S <= CAP) {
        for (int i = s0 + t; i < s1; i += 512) {
            uint w = staging[i];
            int rl = (int)(w >> 17), c = (int)(w & 0x1FFFFu);
            int pos = sc[rl] + atomicAdd(&cnt[rl], 1);
            slice[pos] = c;
        }
        __syncthreads();
        for (int i = t; i < S; i += 512) csr[c0 + i] = slice[i];
    } else {  // safety fallback
        for (int i = s0 + t; i < s1; i += 512) {
            uint w = staging[i];
            int rl = (int)(w >> 17), c = (int)(w & 0x1FFFFu);
            int pos = c0 + sc[rl] + atomicAdd(&cnt[rl], 1);
            csr[pos] = c;
        }
    }
}

// ---------------- x -> bf16 pre-scaled only (dp_in * x) ----------------
__global__ __launch_bounds__(256) void cvt_scaled_kernel(
        const float* __restrict__ in, const float* __restrict__ dp,
        uint* __restrict__ scl, int n8) {
    int i = blockIdx.x * blockDim.x + threadIdx.x;   // 8 floats per thread
    if (i >= n8) return;
    float d = dp[i >> 3];
    const float4 a = ((const float4*)in)[i * 2];
    const float4 b = ((const float4*)in)[i * 2 + 1];
    uintx4 s_;
    s_.x = pack2_rne(a.x * d, a.y * d); s_.y = pack2_rne(a.z * d, a.w * d);
    s_.z = pack2_rne(b.x * d, b.y * d); s_.w = pack2_rne(b.z * d, b.w * d);
    *(uintx4*)&scl[i * 4] = s_;
}

#define ACC8(u)                                        \
    acc[0] += __uint_as_float((u).x << 16);            \
    acc[1] += __uint_as_float((u).x & 0xffff0000u);    \
    acc[2] += __uint_as_float((u).y << 16);            \
    acc[3] += __uint_as_float((u).y & 0xffff0000u);    \
    acc[4] += __uint_as_float((u).z << 16);            \
    acc[5] += __uint_as_float((u).z & 0xffff0000u);    \
    acc[6] += __uint_as_float((u).w << 16);            \
    acc[7] += __uint_as_float((u).w & 0xffff0000u);

// ---------------- forward SpMM: 4 nodes/wave (2 slots x 8 d8 each); fp32 accum
__global__ __launch_bounds__(256) void spmm_fwd_kernel(
        const int* __restrict__ ptr, const int* __restrict__ nbr,
        const float* __restrict__ dp_dst, const float* __restrict__ dp_nxt,
        const ushort* __restrict__ srcs,
        ushort* __restrict__ y_raw, ushort* __restrict__ y_scl, int n, int wscl) {
    int wv = (blockIdx.x * blockDim.x + threadIdx.x) >> 6;
    int lane = threadIdx.x & 63;
    int node = wv * 4 + (lane >> 4);
    int subl = lane & 15;
    int slot = subl >> 3;     // 0..1
    int d8   = subl & 7;      // 8-bf16 group
    bool valid = node < n;
    int beg = valid ? ptr[node] : 0;
    int end = valid ? ptr[node + 1] : 0;
    float acc[8] = {};
    int p = beg + slot;
    for (; p + 6 < end; p += 8) {   // unroll x4: four independent gathers in flight
        int c0 = nbr[p];
        int c1 = nbr[p + 2];
        int c2 = nbr[p + 4];
        int c3 = nbr[p + 6];
        const uintx4 u0 = *(const uintx4*)&srcs[(size_t)c0 * DF + d8 * 8];
        const uintx4 u1 = *(const uintx4*)&srcs[(size_t)c1 * DF + d8 * 8];
        const uintx4 u2 = *(const uintx4*)&srcs[(size_t)c2 * DF + d8 * 8];
        const uintx4 u3 = *(const uintx4*)&srcs[(size_t)c3 * DF + d8 * 8];
        ACC8(u0);
        ACC8(u1);
        ACC8(u2);
        ACC8(u3);
    }
    for (; p < end; p += 2) {
        int c0 = nbr[p];
        const uintx4 u0 = *(const uintx4*)&srcs[(size_t)c0 * DF + d8 * 8];
        ACC8(u0);
    }
    // reduce over the 2 slots (xor 8 — stays within each 16-lane group)
#pragma unroll
    for (int j = 0; j < 8; ++j) acc[j] += __shfl_xor(acc[j], 8);
    if (slot == 0 && valid) {
        float s = dp_dst[node];
        float r0 = acc[0] * s, r1 = acc[1] * s, r2 = acc[2] * s, r3 = acc[3] * s;
        float r4 = acc[4] * s, r5 = acc[5] * s, r6 = acc[6] * s, r7 = acc[7] * s;
        uintx4 o;
        o.x = pack2_rne(r0, r1); o.y = pack2_rne(r2, r3);
        o.z = pack2_rne(r4, r5); o.w = pack2_rne(r6, r7);
        *(uintx4*)&y_raw[(size_t)node * DF + d8 * 8] = o;
        if (wscl) {
            float d = dp_nxt[node];
            uintx4 q;
            q.x = pack2_rne(r0 * d, r1 * d); q.y = pack2_rne(r2 * d, r3 * d);
            q.z = pack2_rne(r4 * d, r5 * d); q.w = pack2_rne(r6 * d, r7 * d);
            *(uintx4*)&y_scl[(size_t)node * DF + d8 * 8] = q;
        }
    }
}

// ---------------- final: 4 nodes/wave; out = oh + dp_in[node] * sum(zb') + bias ----------------
__global__ __launch_bounds__(256) void spmm_final_kernel(
        const int* __restrict__ ptr, const int* __restrict__ nbr,
        const float* __restrict__ dp_dst,
        const ushort* __restrict__ zb, const ushort* __restrict__ oh,
        const float* __restrict__ bias_tot, float* __restrict__ out, int n) {
    int wv = (blockIdx.x * blockDim.x + threadIdx.x) >> 6;
    int lane = threadIdx.x & 63;
    int node = wv * 4 + (lane >> 4);
    int subl = lane & 15;
    int slot = subl >> 3;
    int d8   = subl & 7;
    bool valid = node < n;
    int beg = valid ? ptr[node] : 0;
    int end = valid ? ptr[node + 1] : 0;
    float acc[8] = {};
    int p = beg + slot;
    for (; p + 6 < end; p += 8) {
        int c0 = nbr[p];
        int c1 = nbr[p + 2];
        int c2 = nbr[p + 4];
        int c3 = nbr[p + 6];
        const uintx4 u0 = *(const uintx4*)&zb[(size_t)c0 * DF + d8 * 8];
        const uintx4 u1 = *(const uintx4*)&zb[(size_t)c1 * DF + d8 * 8];
        const uintx4 u2 = *(const uintx4*)&zb[(size_t)c2 * DF + d8 * 8];
        const uintx4 u3 = *(const uintx4*)&zb[(size_t)c3 * DF + d8 * 8];
        ACC8(u0);
        ACC8(u1);
        ACC8(u2);
        ACC8(u3);
    }
    for (; p < end; p += 2) {
        int c0 = nbr[p];
        const uintx4 u0 = *(const uintx4*)&zb[(size_t)c0 * DF + d8 * 8];
        ACC8(u0);
    }
#pragma unroll
    for (int j = 0; j < 8; ++j) acc[j] += __shfl_xor(acc[j], 8);
    if (slot == 0 && valid) {
        float s = dp_dst[node];
        const uintx4 h = *(const uintx4*)&oh[(size_t)node * DF + d8 * 8];
        const float4 b0 = *(const float4*)&bias_tot[d8 * 8];
        const float4 b1 = *(const float4*)&bias_tot[d8 * 8 + 4];
        f32x4 p0, p1;
        p0.x = __uint_as_float(h.x << 16)         + s * acc[0] + b0.x;
        p0.y = __uint_as_float(h.x & 0xffff0000u) + s * acc[1] + b0.y;
        p0.z = __uint_as_float(h.y << 16)         + s * acc[2] + b0.z;
        p0.w = __uint_as_float(h.y & 0xffff0000u) + s * acc[3] + b0.w;
        p1.x = __uint_as_float(h.z << 16)         + s * acc[4] + b1.x;
        p1.y = __uint_as_float(h.z & 0xffff0000u) + s * acc[5] + b1.y;
        p1.z = __uint_as_float(h.w << 16)         + s * acc[6] + b1.z;
        p1.w = __uint_as_float(h.w & 0xffff0000u) + s * acc[7] + b1.w;
        float* op = &out[(size_t)node * DF + d8 * 8];
        *(f32x4*)op = p0;
        *(f32x4*)(op + 4) = p1;
    }
}

// ---------------- fused MFMA GEMM (x read as fp32, converted inline):
//   oh  = bf16( y0*Wb0^T + y1*Wb1^T + y2*Wb2^T )              (0.5*scale in Wb)
//   zb' = bf16( dp_out[row] * (x*Wb3^T + y1*Wb4^T + y2*Wb5^T) )
__global__ __launch_bounds__(256) void gemm_fused_kernel(
        const ushort* __restrict__ y0, const ushort* __restrict__ y1,
        const ushort* __restrict__ y2, const float* __restrict__ xf,
        const ushort* __restrict__ Wb, const float* __restrict__ dp_out,
        ushort* __restrict__ oh, ushort* __restrict__ zb, int n) {
    __shared__ ushort wlds[6 * 4096];
    int t = threadIdx.x;
    for (int f = t; f < 3072; f += 256) {
        int c  = f & 15;
        int kq = (f >> 4) & 3;
        int ks = (f >> 6) & 1;
        int cb = (f >> 7) & 3;
        int m  = f >> 9;
        const uintx4 v = *(const uintx4*)&Wb[m * 4096 + (16 * cb + c) * 64 + ks * 32 + kq * 8];
        *(uintx4*)&wlds[f * 8] = v;
    }
    __syncthreads();
    int w = t >> 6, lane = t & 63;
    int node0 = blockIdx.x * 64 + w * 16;
    int arow = node0 + (lane & 15);
    int kqo = (lane >> 4) * 8;
    f32x4 accO[4] = {};
    f32x4 accZ[4] = {};
#pragma unroll
    for (int ks = 0; ks < 2; ++ks) {
        int aoff = ks * 32 + kqo;
        short8 a0 = {}, a1 = {}, a2 = {}, ax = {};
        if (arow < n) {
            a0 = *(const short8*)&y0[(size_t)arow * DF + aoff];
            a1 = *(const short8*)&y1[(size_t)arow * DF + aoff];
            a2 = *(const short8*)&y2[(size_t)arow * DF + aoff];
            const float4 xa = *(const float4*)&xf[(size_t)arow * DF + aoff];
            const float4 xc = *(const float4*)&xf[(size_t)arow * DF + aoff + 4];
            uintx4 xp;
            xp.x = pack2_rne(xa.x, xa.y); xp.y = pack2_rne(xa.z, xa.w);
            xp.z = pack2_rne(xc.x, xc.y); xp.w = pack2_rne(xc.z, xc.w);
            ax = *(short8*)&xp;
        }
#pragma unroll
        for (int cb = 0; cb < 4; ++cb) {
            const ushort* bp = &wlds[(((cb * 2 + ks) * 64) + lane) * 8];
            short8 b0 = *(const short8*)(bp);
            short8 b1 = *(const short8*)(bp + 4096);
            short8 b2 = *(const short8*)(bp + 8192);
            short8 b3 = *(const short8*)(bp + 12288);
            short8 b4 = *(const short8*)(bp + 16384);
            short8 b5 = *(const short8*)(bp + 20480);
            accO[cb] = __builtin_amdgcn_mfma_f32_16x16x32_bf16(a0, b0, accO[cb], 0, 0, 0);
            accO[cb] = __builtin_amdgcn_mfma_f32_16x16x32_bf16(a1, b1, accO[cb], 0, 0, 0);
            accO[cb] = __builtin_amdgcn_mfma_f32_16x16x32_bf16(a2, b2, accO[cb], 0, 0, 0);
            accZ[cb] = __builtin_amdgcn_mfma_f32_16x16x32_bf16(ax, b3, accZ[cb], 0, 0, 0);
            accZ[cb] = __builtin_amdgcn_mfma_f32_16x16x32_bf16(a1, b4, accZ[cb], 0, 0, 0);
            accZ[cb] = __builtin_amdgcn_mfma_f32_16x16x32_bf16(a2, b5, accZ[cb], 0, 0, 0);
        }
    }
#pragma unroll
    for (int r = 0; r < 4; ++r) {
        int nd = node0 + (lane >> 4) * 4 + r;
        if (nd < n) {
            float d = dp_out[nd];
#pragma unroll
            for (int cb = 0; cb < 4; ++cb) {
                int o = cb * 16 + (lane & 15);
                oh[(size_t)nd * DF + o] = pack1_rne(accO[cb][r]);
                zb[(size_t)nd * DF + o] = pack1_rne(accZ[cb][r] * d);
            }
        }
    }
}

extern "C" void kernel_launch(void* const* d_in, const int* in_sizes, int n_in,
                              void* d_out, int out_size, void* d_ws, size_t ws_size,
                              hipStream_t stream) {
    const int N = N_NODES, E = N_EDGES;
    const float* x    = (const float*)d_in[0];
    const int*   ei   = (const int*)d_in[1];
    const int*   row  = ei;
    const int*   col  = ei + E;
    const float* W_sd = (const float*)d_in[2];
    const float* b_sd = (const float*)d_in[3];
    const float* W_ds = (const float*)d_in[4];
    const float* b_ds = (const float*)d_in[5];
    float* out = (float*)d_out;

    char* ws = (char*)d_ws;
    size_t off = 0;
    auto alloc = [&](size_t bytes) -> void* {
        void* p = ws + off;
        off += (bytes + 255) & ~(size_t)255;
        return p;
    };
    int*   cur_r     = (int*)alloc((size_t)NBUCK * 4);
    int*   cur_c     = (int*)alloc((size_t)NBUCK * 4);
    int*   row_ptr   = (int*)alloc((size_t)(N + 1) * 4);
    int*   col_ptr   = (int*)alloc((size_t)(N + 1) * 4);
    float* dp_out    = (float*)alloc((size_t)N * 4);
    float* dp_in     = (float*)alloc((size_t)N * 4);
    int*   csr_row_col = (int*)alloc((size_t)E * 4);
    int*   csr_col_row = (int*)alloc((size_t)E * 4);
    float* bias_tot  = (float*)alloc(64 * 4);
    ushort* Wb   = (ushort*)alloc((size_t)6 * 4096 * 2);
    ushort* x_s  = (ushort*)alloc((size_t)N * DF * 2);
    ushort* y0   = (ushort*)alloc((size_t)N * DF * 2);
    ushort* y1   = (ushort*)alloc((size_t)N * DF * 2);
    ushort* y2   = (ushort*)alloc((size_t)N * DF * 2);
    ushort* bufA = (ushort*)alloc((size_t)N * DF * 2);  // stg_r -> y0s -> zb
    ushort* bufB = (ushort*)alloc((size_t)N * DF * 2);  // stg_c -> y1s -> oh
    // timeline overlays (each 12.8 MB; staging needs NBUCK*CAPR*4 = 8.03 MB)
    uint*   stg_r = (uint*)bufA;
    uint*   stg_c = (uint*)bufB;
    ushort* y0s = bufA;
    ushort* y1s = bufB;
    ushort* zb  = bufA;
    ushort* oh  = bufB;

    // prologue: weights + bias + staging cursors (one kernel)
    prep_kernel<<<97, 256, 0, stream>>>(W_sd, W_ds, b_sd, b_ds, Wb, bias_tot, cur_r, cur_c);

    const int ablk = (E + CHUNK - 1) / CHUNK;  // 391
    scatter_split_kernel<<<2 * ablk, 256, 0, stream>>>(row, col, cur_r, cur_c,
                                                       stg_r, stg_c, E, ablk);
    degptr_build2_kernel<<<2 * NBUCK, 512, 0, stream>>>(
        cur_r, cur_c, stg_r, stg_c,
        row_ptr, col_ptr, dp_out, dp_in, csr_row_col, csr_col_row, N);

    const int n8 = N * DF / 8;
    cvt_scaled_kernel<<<(n8 + 255) / 256, 256, 0, stream>>>(x, dp_in, (uint*)x_s, n8);

    const int spmm_blk = (N * 16 + 255) / 256;   // 4 nodes per wave
    const int gblk = (N + 63) / 64;

    // forward chain (gathers read pre-scaled tables; no per-edge dp loads)
    spmm_fwd_kernel<<<spmm_blk, 256, 0, stream>>>(row_ptr, csr_row_col, dp_out, dp_in,
                                                  x_s, y0, y0s, N, 1);
    spmm_fwd_kernel<<<spmm_blk, 256, 0, stream>>>(row_ptr, csr_row_col, dp_out, dp_in,
                                                  y0s, y1, y1s, N, 1);
    spmm_fwd_kernel<<<spmm_blk, 256, 0, stream>>>(row_ptr, csr_row_col, dp_out, dp_in,
                                                  y1s, y2, (ushort*)0, N, 0);

    // oh = bf16(0.5*sum y_i Wsd_i^T) ; zb = bf16(dp_out * 0.5*(x Wds0 + 0.5 y1 Wds1 + 0.25 y2 Wds2))
    gemm_fused_kernel<<<gblk, 256, 0, stream>>>(y0, y1, y2, x, Wb, dp_out, oh, zb, N);

    // out = oh + dp_in * (A^T-gather of zb) + bias
    spmm_final_kernel<<<spmm_blk, 256, 0, stream>>>(col_ptr, csr_col_row, dp_in,
                                                    zb, oh, bias_tot, out, N);
}